// Round 1
// baseline (5447.038 us; speedup 1.0000x reference)
//
#include <hip/hip_runtime.h>
#include <hip/hip_bf16.h>
#include <cstddef>

// Problem constants
#define B_   2
#define S_   2048
#define D_   2048
#define H_   16
#define HD_  128
#define N3_  6144            // 3*D
#define M_   4096            // B*S
#define REG_ 8388608         // B*H*S*HD floats per q/k/v region
#define HROW_ 262144         // S*HD (per (b,h) row block)

// ---------------------------------------------------------------------------
// Kernel 1: qkv = x @ qkv_w + qkv_b, scatter-stored head-major:
//   qkv_hm[which][b][h][s][hd], which in {0=q,1=k,2=v}
// Tiled SGEMM: BM=128, BN=64, BK=16, 256 threads, 8x4 per thread.
// ---------------------------------------------------------------------------
__global__ __launch_bounds__(256) void qkv_gemm_kernel(
    const float* __restrict__ x, const float* __restrict__ w,
    const float* __restrict__ bias, float* __restrict__ qkv)
{
    __shared__ float As[128][17];   // +1 pad breaks 16-row bank aliasing
    __shared__ float Bs[16][64];

    const int tid  = threadIdx.x;
    const int tm   = tid >> 4;           // 0..15 (M direction)
    const int tn   = tid & 15;           // 0..15 (N direction)
    const int row0 = blockIdx.x * 128;
    const int col0 = blockIdx.y * 64;

    float acc[8][4];
    #pragma unroll
    for (int r = 0; r < 8; ++r)
        #pragma unroll
        for (int c = 0; c < 4; ++c) acc[r][c] = 0.f;

    for (int k0 = 0; k0 < D_; k0 += 16) {
        // Load A tile 128x16 (512 float4, 2 per thread)
        #pragma unroll
        for (int i = 0; i < 2; ++i) {
            int e = tid + i * 256;           // 0..511
            int r = e >> 2;                  // 0..127
            int c = (e & 3) * 4;             // 0,4,8,12
            float4 v = *reinterpret_cast<const float4*>(
                &x[(size_t)(row0 + r) * D_ + k0 + c]);
            As[r][c + 0] = v.x; As[r][c + 1] = v.y;
            As[r][c + 2] = v.z; As[r][c + 3] = v.w;
        }
        // Load B tile 16x64 (256 float4, 1 per thread)
        {
            int r = tid >> 4;                // 0..15
            int c = (tid & 15) * 4;          // 0..60
            float4 v = *reinterpret_cast<const float4*>(
                &w[(size_t)(k0 + r) * N3_ + col0 + c]);
            *reinterpret_cast<float4*>(&Bs[r][c]) = v;
        }
        __syncthreads();

        #pragma unroll
        for (int k = 0; k < 16; ++k) {
            float4 bv = *reinterpret_cast<const float4*>(&Bs[k][tn * 4]);
            #pragma unroll
            for (int r = 0; r < 8; ++r) {
                float a = As[tm * 8 + r][k];
                acc[r][0] += a * bv.x; acc[r][1] += a * bv.y;
                acc[r][2] += a * bv.z; acc[r][3] += a * bv.w;
            }
        }
        __syncthreads();
    }

    // Epilogue: bias + scatter to head-major layout (float4 per row)
    const int gcol  = col0 + tn * 4;         // 0..6140, 4-aligned, within one head half
    const int which = gcol >> 11;            // /2048
    const int dcol  = gcol & 2047;
    const int h     = dcol >> 7;
    const int hd    = dcol & 127;
    const float4 bv = *reinterpret_cast<const float4*>(&bias[gcol]);

    #pragma unroll
    for (int r = 0; r < 8; ++r) {
        int grow = row0 + tm * 8 + r;        // 0..4095
        int b    = grow >> 11;
        int s    = grow & 2047;
        float4 o;
        o.x = acc[r][0] + bv.x; o.y = acc[r][1] + bv.y;
        o.z = acc[r][2] + bv.z; o.w = acc[r][3] + bv.w;
        size_t dst = (size_t)which * REG_ + (size_t)(b * H_ + h) * HROW_
                   + (size_t)s * HD_ + hd;
        *reinterpret_cast<float4*>(&qkv[dst]) = o;
    }
}

// ---------------------------------------------------------------------------
// Kernel 2: RoPE in place on Q and K regions (contiguous 131072 rows of 128).
// out[d]    = x[d]*cos[s,d]   - x[d+64]*sin[s,d]
// out[d+64] = x[d+64]*cos[s,d] + x[d]*sin[s,d]     (cos/sin repeat at d+64)
// ---------------------------------------------------------------------------
__global__ __launch_bounds__(256) void rope_kernel(
    float* __restrict__ qk, const float* __restrict__ cosn,
    const float* __restrict__ sinn)
{
    int p = blockIdx.x * 256 + threadIdx.x;  // 0 .. 2*B*H*S*64 - 1
    int d = p & 63;
    int r = p >> 6;                          // row id 0..131071
    int s = r & 2047;                        // position within sequence
    float* row = qk + (size_t)r * HD_;
    float c  = cosn[s * HD_ + d];
    float sn = sinn[s * HD_ + d];
    float lo = row[d];
    float hi = row[d + 64];
    row[d]      = lo * c - hi * sn;
    row[d + 64] = hi * c + lo * sn;
}

// ---------------------------------------------------------------------------
// Kernel 3: causal flash attention, fp32.
// Block: 256 threads (4 waves). Q tile = 16 rows, K/V tile = 64 rows.
// Score phase: wave w owns rows i = 4w..4w+3; lane j = key index in tile.
// PV phase: thread (oi = tid>>4, og = tid&15) accumulates O[oi][og*8..og*8+7].
// ---------------------------------------------------------------------------
#define QT_ 16
#define KT_ 64
__global__ __launch_bounds__(256) void attn_kernel(
    const float* __restrict__ Q, const float* __restrict__ K,
    const float* __restrict__ V, float* __restrict__ AO)
{
    __shared__ float Qs[QT_][132];
    __shared__ float Ks[KT_][132];
    __shared__ float Vs[KT_][132];
    __shared__ float Ps[QT_][64];
    __shared__ float mRow[QT_], lRow[QT_], scRow[QT_];

    const int tid = threadIdx.x;
    const int qt  = blockIdx.x;          // 0..127
    const int bh  = blockIdx.y;          // 0..31
    const int q0  = qt * QT_;
    const float* Qb = Q + (size_t)bh * HROW_;
    const float* Kb = K + (size_t)bh * HROW_;
    const float* Vb = V + (size_t)bh * HROW_;
    const float rs = 0.08838834764831845f;   // 1/sqrt(128)

    // Load Q tile, pre-scaled (512 float4, 2 per thread)
    #pragma unroll
    for (int i = 0; i < 2; ++i) {
        int e = tid + i * 256;               // float4 slot 0..511
        int r = e >> 5;                      // 0..15
        int c = (e & 31) * 4;                // 0..124
        float4 v = *reinterpret_cast<const float4*>(
            &Qb[(size_t)(q0 + r) * HD_ + c]);
        Qs[r][c + 0] = v.x * rs; Qs[r][c + 1] = v.y * rs;
        Qs[r][c + 2] = v.z * rs; Qs[r][c + 3] = v.w * rs;
    }
    if (tid < QT_) { mRow[tid] = -1e30f; lRow[tid] = 0.f; }

    const int j  = tid & 63;             // key lane within tile
    const int w  = tid >> 6;             // wave id -> q rows 4w..4w+3
    const int oi = tid >> 4;             // PV row
    const int og = tid & 15;             // PV d-group (8 floats)
    float oacc[8];
    #pragma unroll
    for (int t = 0; t < 8; ++t) oacc[t] = 0.f;

    const int nkt = (q0 + QT_ - 1) / KT_ + 1;
    for (int kt = 0; kt < nkt; ++kt) {
        const int k0 = kt * KT_;
        // Load K and V tiles (each 64x128 = 2048 float4, 8 per thread each)
        #pragma unroll
        for (int i = 0; i < 8; ++i) {
            int e = tid + i * 256;           // 0..2047
            int r = e >> 5;                  // 0..63
            int c = (e & 31) * 4;
            *reinterpret_cast<float4*>(&Ks[r][c]) =
                *reinterpret_cast<const float4*>(&Kb[(size_t)(k0 + r) * HD_ + c]);
            *reinterpret_cast<float4*>(&Vs[r][c]) =
                *reinterpret_cast<const float4*>(&Vb[(size_t)(k0 + r) * HD_ + c]);
        }
        __syncthreads();

        // ---- scores: sacc[ii] = q_{4w+ii} . k_j ----
        float sacc[4] = {0.f, 0.f, 0.f, 0.f};
        for (int d = 0; d < HD_; d += 4) {
            float4 kv = *reinterpret_cast<const float4*>(&Ks[j][d]);
            #pragma unroll
            for (int ii = 0; ii < 4; ++ii) {
                float4 qv = *reinterpret_cast<const float4*>(&Qs[w * 4 + ii][d]);
                sacc[ii] += qv.x * kv.x + qv.y * kv.y + qv.z * kv.z + qv.w * kv.w;
            }
        }

        const int jabs = k0 + j;
        #pragma unroll
        for (int ii = 0; ii < 4; ++ii) {
            int i    = w * 4 + ii;
            int iabs = q0 + i;
            float sv = (jabs <= iabs) ? sacc[ii] : -1e30f;
            float mt = sv;
            #pragma unroll
            for (int off = 32; off; off >>= 1)
                mt = fmaxf(mt, __shfl_xor(mt, off));
            float mprev = mRow[i];
            float mnew  = fmaxf(mprev, mt);
            float p     = __expf(sv - mnew);
            float psum  = p;
            #pragma unroll
            for (int off = 32; off; off >>= 1)
                psum += __shfl_xor(psum, off);
            Ps[i][j] = p;
            if (j == 0) {
                float sc = __expf(mprev - mnew);
                scRow[i] = sc;
                mRow[i]  = mnew;
                lRow[i]  = lRow[i] * sc + psum;
            }
        }
        __syncthreads();

        // ---- PV: O[oi][og*8..] = O*sc + P[oi][:] @ V[:, og*8..] ----
        {
            float sc = scRow[oi];
            #pragma unroll
            for (int t = 0; t < 8; ++t) oacc[t] *= sc;
            for (int jj = 0; jj < KT_; ++jj) {
                float p = Ps[oi][jj];
                float4 v0 = *reinterpret_cast<const float4*>(&Vs[jj][og * 8]);
                float4 v1 = *reinterpret_cast<const float4*>(&Vs[jj][og * 8 + 4]);
                oacc[0] += p * v0.x; oacc[1] += p * v0.y;
                oacc[2] += p * v0.z; oacc[3] += p * v0.w;
                oacc[4] += p * v1.x; oacc[5] += p * v1.y;
                oacc[6] += p * v1.z; oacc[7] += p * v1.w;
            }
        }
        __syncthreads();   // protect Ks/Vs/Ps before next tile overwrites
    }

    // Final normalize + store head-major AO[b][h][q0+oi][:]
    {
        float inv = 1.0f / lRow[oi];
        float* dst = AO + (size_t)bh * HROW_ + (size_t)(q0 + oi) * HD_ + og * 8;
        float4 o0, o1;
        o0.x = oacc[0] * inv; o0.y = oacc[1] * inv;
        o0.z = oacc[2] * inv; o0.w = oacc[3] * inv;
        o1.x = oacc[4] * inv; o1.y = oacc[5] * inv;
        o1.z = oacc[6] * inv; o1.w = oacc[7] * inv;
        *reinterpret_cast<float4*>(dst)     = o0;
        *reinterpret_cast<float4*>(dst + 4) = o1;
    }
}

// ---------------------------------------------------------------------------
// Kernel 4: out = AO(gathered to [B,S,D]) @ out_w + out_b
// Same SGEMM structure as kernel 1; A rows gathered from head-major AO.
// ---------------------------------------------------------------------------
__global__ __launch_bounds__(256) void out_gemm_kernel(
    const float* __restrict__ AO, const float* __restrict__ w,
    const float* __restrict__ bias, float* __restrict__ out)
{
    __shared__ float As[128][17];
    __shared__ float Bs[16][64];

    const int tid  = threadIdx.x;
    const int tm   = tid >> 4;
    const int tn   = tid & 15;
    const int row0 = blockIdx.x * 128;
    const int col0 = blockIdx.y * 64;

    float acc[8][4];
    #pragma unroll
    for (int r = 0; r < 8; ++r)
        #pragma unroll
        for (int c = 0; c < 4; ++c) acc[r][c] = 0.f;

    for (int k0 = 0; k0 < D_; k0 += 16) {
        #pragma unroll
        for (int i = 0; i < 2; ++i) {
            int e  = tid + i * 256;
            int r  = e >> 2;                 // 0..127
            int cc = (e & 3) * 4;            // 0..12
            int grow = row0 + r;
            int b  = grow >> 11;
            int s  = grow & 2047;
            int kk = k0 + cc;                // 16-aligned chunk, same head
            int h  = kk >> 7;
            int hd = kk & 127;
            float4 v = *reinterpret_cast<const float4*>(
                &AO[(size_t)(b * H_ + h) * HROW_ + (size_t)s * HD_ + hd]);
            As[r][cc + 0] = v.x; As[r][cc + 1] = v.y;
            As[r][cc + 2] = v.z; As[r][cc + 3] = v.w;
        }
        {
            int r = tid >> 4;
            int c = (tid & 15) * 4;
            float4 v = *reinterpret_cast<const float4*>(
                &w[(size_t)(k0 + r) * D_ + col0 + c]);
            *reinterpret_cast<float4*>(&Bs[r][c]) = v;
        }
        __syncthreads();

        #pragma unroll
        for (int k = 0; k < 16; ++k) {
            float4 bv = *reinterpret_cast<const float4*>(&Bs[k][tn * 4]);
            #pragma unroll
            for (int r = 0; r < 8; ++r) {
                float a = As[tm * 8 + r][k];
                acc[r][0] += a * bv.x; acc[r][1] += a * bv.y;
                acc[r][2] += a * bv.z; acc[r][3] += a * bv.w;
            }
        }
        __syncthreads();
    }

    const int gcol = col0 + tn * 4;
    const float4 bv = *reinterpret_cast<const float4*>(&bias[gcol]);
    #pragma unroll
    for (int r = 0; r < 8; ++r) {
        int grow = row0 + tm * 8 + r;
        float4 o;
        o.x = acc[r][0] + bv.x; o.y = acc[r][1] + bv.y;
        o.z = acc[r][2] + bv.z; o.w = acc[r][3] + bv.w;
        *reinterpret_cast<float4*>(&out[(size_t)grow * D_ + gcol]) = o;
    }
}

// ---------------------------------------------------------------------------
extern "C" void kernel_launch(void* const* d_in, const int* in_sizes, int n_in,
                              void* d_out, int out_size, void* d_ws, size_t ws_size,
                              hipStream_t stream)
{
    (void)in_sizes; (void)n_in; (void)out_size; (void)ws_size;
    const float* x      = (const float*)d_in[0];
    const float* cosn   = (const float*)d_in[1];
    const float* sinn   = (const float*)d_in[2];
    const float* qkv_w  = (const float*)d_in[3];
    const float* qkv_b  = (const float*)d_in[4];
    const float* out_w  = (const float*)d_in[5];
    const float* out_b  = (const float*)d_in[6];
    float* out = (float*)d_out;

    // ws layout (floats): [0, 3*REG_) = Q,K,V head-major; [3*REG_, 4*REG_) = AO
    float* qkv_hm = (float*)d_ws;
    float* Qp = qkv_hm;
    float* Kp = qkv_hm + (size_t)REG_;
    float* Vp = qkv_hm + (size_t)2 * REG_;
    float* AO = qkv_hm + (size_t)3 * REG_;

    hipLaunchKernelGGL(qkv_gemm_kernel, dim3(32, 96), dim3(256), 0, stream,
                       x, qkv_w, qkv_b, qkv_hm);
    hipLaunchKernelGGL(rope_kernel, dim3(32768), dim3(256), 0, stream,
                       qkv_hm, cosn, sinn);   // covers Q then K contiguously
    hipLaunchKernelGGL(attn_kernel, dim3(128, 32), dim3(256), 0, stream,
                       Qp, Kp, Vp, AO);
    hipLaunchKernelGGL(out_gemm_kernel, dim3(32, 32), dim3(256), 0, stream,
                       AO, out_w, out_b, out);
}

// Round 2
// 599.173 us; speedup vs baseline: 9.0909x; 9.0909x over previous
//
#include <hip/hip_runtime.h>
#include <cstddef>
#include <cstdint>

// ---------------- types / helpers ----------------
typedef __attribute__((ext_vector_type(8))) short bh8_t;  // 8 bf16 (4 VGPRs)
typedef __attribute__((ext_vector_type(4))) float f4_t;   // MFMA accumulator

__device__ __forceinline__ unsigned short f2bf(float x) {
    union { float f; unsigned u; } v; v.f = x;
    unsigned r = v.u + 0x7fffu + ((v.u >> 16) & 1u);   // RN-even
    return (unsigned short)(r >> 16);
}
__device__ __forceinline__ float bf2f(unsigned short u) {
    union { unsigned u; float f; } v; v.u = ((unsigned)u) << 16;
    return v.f;
}

// Problem constants
#define B_    2
#define S_    2048
#define D_    2048
#define H_    16
#define HD_   128

// ---------------------------------------------------------------------------
// x (f32) -> bf16, same layout. 8 elems/thread.
// ---------------------------------------------------------------------------
__global__ __launch_bounds__(256) void cvt_f32_bf16(const float* __restrict__ in,
                                                    ushort* __restrict__ out) {
    size_t i = ((size_t)blockIdx.x * 256 + threadIdx.x) * 8;
    float4 a = *(const float4*)&in[i];
    float4 b = *(const float4*)&in[i + 4];
    ushort4 o0, o1;
    o0.x = f2bf(a.x); o0.y = f2bf(a.y); o0.z = f2bf(a.z); o0.w = f2bf(a.w);
    o1.x = f2bf(b.x); o1.y = f2bf(b.y); o1.z = f2bf(b.z); o1.w = f2bf(b.w);
    *(ushort4*)&out[i]     = o0;
    *(ushort4*)&out[i + 4] = o1;
}

// ---------------------------------------------------------------------------
// W[R][C] f32  ->  Wt[C][R] bf16   (64x64 LDS tile transpose)
// ---------------------------------------------------------------------------
__global__ __launch_bounds__(256) void transp_f32_bf16(const float* __restrict__ in,
                                                       ushort* __restrict__ out,
                                                       int R, int C) {
    __shared__ float T[64][68];           // 68: 16B-aligned rows, odd-ish bank spread
    const int t = threadIdx.x, rl = t >> 4, cl = t & 15;
    const int r0 = blockIdx.y * 64, c0 = blockIdx.x * 64;
    #pragma unroll
    for (int j = 0; j < 4; ++j) {
        int row = rl + 16 * j;
        float4 v = *(const float4*)&in[(size_t)(r0 + row) * C + c0 + cl * 4];
        *(float4*)&T[row][cl * 4] = v;
    }
    __syncthreads();
    #pragma unroll
    for (int j = 0; j < 4; ++j) {
        int row = rl + 16 * j;            // out row = c0+row (an input column)
        ushort4 o;
        o.x = f2bf(T[cl * 4 + 0][row]);
        o.y = f2bf(T[cl * 4 + 1][row]);
        o.z = f2bf(T[cl * 4 + 2][row]);
        o.w = f2bf(T[cl * 4 + 3][row]);
        *(ushort4*)&out[(size_t)(c0 + row) * R + r0 + cl * 4] = o;
    }
}

// ---------------------------------------------------------------------------
// QKV GEMM: C[4096][6144] = xb[4096][2048] * wtb[6144][2048]^T + bias
// 128x128 tile, BK=32, 4 waves (2x2 of 64x64), 16x16x32 bf16 MFMA.
// Epilogue scatters bf16 into head-major Qb/Kb/Vb [b][h][s][hd].
// ---------------------------------------------------------------------------
__global__ __launch_bounds__(256) void qkv_gemm(const ushort* __restrict__ A,
                                                const ushort* __restrict__ Bt,
                                                const float* __restrict__ bias,
                                                ushort* __restrict__ Qb,
                                                ushort* __restrict__ Kb,
                                                ushort* __restrict__ Vb) {
    __shared__ ushort Al[128 * 32];
    __shared__ ushort Bl[128 * 32];
    const int tid = threadIdx.x;
    const int l = tid & 63, wv = tid >> 6;
    const int lr = l & 15, bk = l >> 4;
    const int wr = wv >> 1, wc = wv & 1;
    const int row0 = blockIdx.x * 128, col0 = blockIdx.y * 128;

    f4_t zero4 = {0.f, 0.f, 0.f, 0.f};
    f4_t acc[4][4];
    #pragma unroll
    for (int i = 0; i < 4; ++i)
        #pragma unroll
        for (int j = 0; j < 4; ++j) acc[i][j] = zero4;

    // staging: 512 16B-chunks per tile; thread owns chunks tid and tid+256
    const int ra0 = tid >> 2,         pa0 = tid & 3;
    const int ra1 = (tid + 256) >> 2, pa1 = (tid + 256) & 3;
    const ushort* Ap0 = A  + (size_t)(row0 + ra0) * 2048 + pa0 * 8;
    const ushort* Ap1 = A  + (size_t)(row0 + ra1) * 2048 + pa1 * 8;
    const ushort* Bp0 = Bt + (size_t)(col0 + ra0) * 2048 + pa0 * 8;
    const ushort* Bp1 = Bt + (size_t)(col0 + ra1) * 2048 + pa1 * 8;

    uint4 sa0 = *(const uint4*)Ap0, sa1 = *(const uint4*)Ap1;
    uint4 sb0 = *(const uint4*)Bp0, sb1 = *(const uint4*)Bp1;

    for (int k0 = 0; k0 < 2048; k0 += 32) {
        *(uint4*)&Al[ra0 * 32 + pa0 * 8] = sa0;
        *(uint4*)&Al[ra1 * 32 + pa1 * 8] = sa1;
        *(uint4*)&Bl[ra0 * 32 + pa0 * 8] = sb0;
        *(uint4*)&Bl[ra1 * 32 + pa1 * 8] = sb1;
        __syncthreads();
        if (k0 + 32 < 2048) {                     // prefetch next K-slab early
            sa0 = *(const uint4*)(Ap0 + k0 + 32);
            sa1 = *(const uint4*)(Ap1 + k0 + 32);
            sb0 = *(const uint4*)(Bp0 + k0 + 32);
            sb1 = *(const uint4*)(Bp1 + k0 + 32);
        }
        bh8_t af[4], bf[4];
        #pragma unroll
        for (int mf = 0; mf < 4; ++mf)
            af[mf] = *(const bh8_t*)&Al[(wr * 64 + mf * 16 + lr) * 32 + bk * 8];
        #pragma unroll
        for (int nf = 0; nf < 4; ++nf)
            bf[nf] = *(const bh8_t*)&Bl[(wc * 64 + nf * 16 + lr) * 32 + bk * 8];
        #pragma unroll
        for (int mf = 0; mf < 4; ++mf)
            #pragma unroll
            for (int nf = 0; nf < 4; ++nf)
                acc[mf][nf] = __builtin_amdgcn_mfma_f32_16x16x32_bf16(
                    af[mf], bf[nf], acc[mf][nf], 0, 0, 0);
        __syncthreads();
    }

    // epilogue: whole block lies in one head (128 cols) of one of q/k/v
    const int which = col0 >> 11;
    const int h = (col0 & 2047) >> 7;
    ushort* dst = which == 0 ? Qb : (which == 1 ? Kb : Vb);
    #pragma unroll
    for (int nf = 0; nf < 4; ++nf) {
        int n = col0 + wc * 64 + nf * 16 + lr;
        float bv = bias[n];
        int hd = wc * 64 + nf * 16 + lr;
        #pragma unroll
        for (int mf = 0; mf < 4; ++mf) {
            int mbase = row0 + wr * 64 + mf * 16 + bk * 4;
            #pragma unroll
            for (int r = 0; r < 4; ++r) {
                int m = mbase + r;
                int b = m >> 11, s = m & 2047;
                dst[((size_t)(b * 16 + h) * 2048 + s) * 128 + hd] =
                    f2bf(acc[mf][nf][r] + bv);
            }
        }
    }
}

// ---------------------------------------------------------------------------
// RoPE in place on bf16 Qb/Kb (head-major). Q additionally pre-scaled by
// 1/sqrt(128). cos/sin repeat at d+64 so only [s][0..63] is used.
// ---------------------------------------------------------------------------
__global__ __launch_bounds__(256) void rope_bf16(ushort* __restrict__ Qb,
                                                 ushort* __restrict__ Kb,
                                                 const float* __restrict__ cosn,
                                                 const float* __restrict__ sinn) {
    unsigned idx = blockIdx.x * 256 + threadIdx.x;   // 2 * 65536 * 16
    int regn = idx >> 20;
    unsigned rest = idx & 1048575u;
    unsigned row = rest >> 4;                        // (b*16+h)*2048 + s
    int g = rest & 15;                               // 4-wide d group
    int s = row & 2047;
    ushort* base = (regn ? Kb : Qb) + (size_t)row * 128 + g * 4;
    uint2 lo = *(const uint2*)base;
    uint2 hi = *(const uint2*)(base + 64);
    float4 c4 = *(const float4*)&cosn[s * 128 + g * 4];
    float4 s4 = *(const float4*)&sinn[s * 128 + g * 4];
    const float sc = regn ? 1.0f : 0.08838834764831845f;
    const ushort* lp = (const ushort*)&lo;
    const ushort* hp = (const ushort*)&hi;
    float cf[4] = {c4.x, c4.y, c4.z, c4.w};
    float sf[4] = {s4.x, s4.y, s4.z, s4.w};
    ushort4 olo, ohi;
    ushort* olp = (ushort*)&olo;
    ushort* ohp = (ushort*)&ohi;
    #pragma unroll
    for (int e = 0; e < 4; ++e) {
        float lv = bf2f(lp[e]), hv = bf2f(hp[e]);
        olp[e] = f2bf((lv * cf[e] - hv * sf[e]) * sc);
        ohp[e] = f2bf((hv * cf[e] + lv * sf[e]) * sc);
    }
    *(ushort4*)base        = olo;
    *(ushort4*)(base + 64) = ohi;
}

// ---------------------------------------------------------------------------
// Flash attention, bf16 MFMA, causal. Block = 4 waves, 64 q-rows (16/wave),
// K/V tile = 64 keys. Swapped QK^T (S^T = K*Q^T) keeps softmax per-lane;
// P^T fragments feed PV directly as the B operand. K and V^T tiles live in
// LDS with XOR bank-swizzle ^((row&7)<<4).
// ---------------------------------------------------------------------------
__global__ __launch_bounds__(256) void attn_mfma(const ushort* __restrict__ Qb,
                                                 const ushort* __restrict__ Kb,
                                                 const ushort* __restrict__ Vb,
                                                 ushort* __restrict__ AO) {
    __shared__ ushort Kl[64 * 128];   // [key][hd], swizzled
    __shared__ ushort Vt[128 * 64];   // [d][key],  swizzled
    const int tid = threadIdx.x;
    const int l = tid & 63, wq = tid >> 6;
    const int lr = l & 15, bk = l >> 4;
    const int qb = (int)gridDim.x - 1 - (int)blockIdx.x;   // heavy blocks first
    const int bh = blockIdx.y;
    const int q0 = qb * 64;
    const int qrow = q0 + wq * 16 + lr;
    const ushort* Qg = Qb + ((size_t)bh * 2048 + qrow) * 128;

    bh8_t qf[4];
    #pragma unroll
    for (int ks = 0; ks < 4; ++ks)
        qf[ks] = *(const bh8_t*)(Qg + ks * 32 + bk * 8);

    float mrun = -1e30f, lrun = 0.f;
    f4_t zero4 = {0.f, 0.f, 0.f, 0.f};
    f4_t oacc[8];
    #pragma unroll
    for (int i = 0; i < 8; ++i) oacc[i] = zero4;

    const int srow = tid >> 4, sslot = tid & 15;
    uint4 kreg[4], v0reg[2], v1reg[2];

    auto load_tile = [&](int kt) {
        const ushort* Kg = Kb + ((size_t)bh * 2048 + kt * 64) * 128;
        const ushort* Vg = Vb + ((size_t)bh * 2048 + kt * 64) * 128;
        #pragma unroll
        for (int j = 0; j < 4; ++j)
            kreg[j] = *(const uint4*)(Kg + (size_t)(srow + 16 * j) * 128 + sslot * 8);
        #pragma unroll
        for (int u = 0; u < 2; ++u) {
            int kp = srow + 16 * u;
            v0reg[u] = *(const uint4*)(Vg + (size_t)(2 * kp) * 128 + sslot * 8);
            v1reg[u] = *(const uint4*)(Vg + (size_t)(2 * kp + 1) * 128 + sslot * 8);
        }
    };
    auto store_tile = [&]() {
        #pragma unroll
        for (int j = 0; j < 4; ++j) {
            int row = srow + 16 * j;
            int db = (row * 256 + sslot * 16) ^ ((row & 7) << 4);
            *(uint4*)((char*)Kl + db) = kreg[j];
        }
        #pragma unroll
        for (int u = 0; u < 2; ++u) {
            int kp = srow + 16 * u;
            const ushort* e0 = (const ushort*)&v0reg[u];
            const ushort* e1 = (const ushort*)&v1reg[u];
            #pragma unroll
            for (int e = 0; e < 8; ++e) {
                int d = sslot * 8 + e;
                unsigned wvv = (unsigned)e0[e] | ((unsigned)e1[e] << 16);
                int db = (d * 128 + kp * 4) ^ ((d & 7) << 4);
                *(unsigned*)((char*)Vt + db) = wvv;
            }
        }
    };

    load_tile(0);
    for (int kt = 0; kt <= qb; ++kt) {
        store_tile();
        __syncthreads();
        if (kt < qb) load_tile(kt + 1);   // hide HBM latency under compute

        // ---- S^T = K * Q^T  (16 MFMAs) ----
        f4_t sacc[4];
        #pragma unroll
        for (int kf = 0; kf < 4; ++kf) sacc[kf] = zero4;
        #pragma unroll
        for (int ks = 0; ks < 4; ++ks) {
            #pragma unroll
            for (int kf = 0; kf < 4; ++kf) {
                int key = kf * 16 + lr;
                int ab = (key * 256 + ks * 64 + bk * 16) ^ ((key & 7) << 4);
                bh8_t kv = *(const bh8_t*)((char*)Kl + ab);
                sacc[kf] = __builtin_amdgcn_mfma_f32_16x16x32_bf16(
                    kv, qf[ks], sacc[kf], 0, 0, 0);
            }
        }
        // ---- causal mask (only the diagonal tile) ----
        if (kt == qb) {
            #pragma unroll
            for (int kf = 0; kf < 4; ++kf)
                #pragma unroll
                for (int r = 0; r < 4; ++r) {
                    int key = kt * 64 + kf * 16 + bk * 4 + r;
                    if (key > qrow) sacc[kf][r] = -1e30f;
                }
        }
        // ---- online softmax (per-lane, + xor16/32 across key groups) ----
        float mt = -1e30f;
        #pragma unroll
        for (int kf = 0; kf < 4; ++kf)
            #pragma unroll
            for (int r = 0; r < 4; ++r) mt = fmaxf(mt, sacc[kf][r]);
        mt = fmaxf(mt, __shfl_xor(mt, 16));
        mt = fmaxf(mt, __shfl_xor(mt, 32));
        float mnew = fmaxf(mrun, mt);
        float alpha = __expf(mrun - mnew);
        float rsum = 0.f;
        #pragma unroll
        for (int kf = 0; kf < 4; ++kf)
            #pragma unroll
            for (int r = 0; r < 4; ++r) {
                float p = __expf(sacc[kf][r] - mnew);
                sacc[kf][r] = p;
                rsum += p;
            }
        rsum += __shfl_xor(rsum, 16);
        rsum += __shfl_xor(rsum, 32);
        lrun = lrun * alpha + rsum;
        mrun = mnew;
        #pragma unroll
        for (int df = 0; df < 8; ++df) oacc[df] *= alpha;

        // ---- pack P^T to bf16 B-operands ----
        union { unsigned u[4]; bh8_t v; } bop[2];
        #pragma unroll
        for (int ks2 = 0; ks2 < 2; ++ks2)
            #pragma unroll
            for (int e = 0; e < 8; e += 2) {
                unsigned lo16 = f2bf(sacc[2 * ks2 + (e >> 2)][e & 3]);
                unsigned hi16 = f2bf(sacc[2 * ks2 + ((e + 1) >> 2)][(e + 1) & 3]);
                bop[ks2].u[e >> 1] = lo16 | (hi16 << 16);
            }
        // ---- O^T += V^T * P^T  (16 MFMAs) ----
        #pragma unroll
        for (int df = 0; df < 8; ++df) {
            int d = df * 16 + lr;
            int rowb = d * 128;
            int swz = (d & 7) << 4;
            #pragma unroll
            for (int ks2 = 0; ks2 < 2; ++ks2) {
                int b0 = rowb + ks2 * 64 + bk * 8;
                uint2 vlo = *(const uint2*)((char*)Vt + (b0 ^ swz));
                uint2 vhi = *(const uint2*)((char*)Vt + ((b0 + 32) ^ swz));
                union { unsigned u[4]; bh8_t v; } av;
                av.u[0] = vlo.x; av.u[1] = vlo.y; av.u[2] = vhi.x; av.u[3] = vhi.y;
                oacc[df] = __builtin_amdgcn_mfma_f32_16x16x32_bf16(
                    av.v, bop[ks2].v, oacc[df], 0, 0, 0);
            }
        }
        __syncthreads();
    }

    // ---- normalize + store bf16 to AO[B*S][D] (row = own q, 8B chunks) ----
    float inv = 1.0f / lrun;
    const int b = bh >> 4, h = bh & 15;
    #pragma unroll
    for (int df = 0; df < 8; ++df) {
        ushort4 o;
        o.x = f2bf(oacc[df][0] * inv);
        o.y = f2bf(oacc[df][1] * inv);
        o.z = f2bf(oacc[df][2] * inv);
        o.w = f2bf(oacc[df][3] * inv);
        size_t off = ((size_t)(b * 2048 + qrow)) * 2048 + h * 128 + df * 16 + bk * 4;
        *(ushort4*)&AO[off] = o;
    }
}

// ---------------------------------------------------------------------------
// Out projection: out[4096][2048] = AO[4096][2048] * owtb[2048][2048]^T + b
// Same GEMM core, fp32 output.
// ---------------------------------------------------------------------------
__global__ __launch_bounds__(256) void out_gemm(const ushort* __restrict__ A,
                                                const ushort* __restrict__ Bt,
                                                const float* __restrict__ bias,
                                                float* __restrict__ out) {
    __shared__ ushort Al[128 * 32];
    __shared__ ushort Bl[128 * 32];
    const int tid = threadIdx.x;
    const int l = tid & 63, wv = tid >> 6;
    const int lr = l & 15, bk = l >> 4;
    const int wr = wv >> 1, wc = wv & 1;
    const int row0 = blockIdx.x * 128, col0 = blockIdx.y * 128;

    f4_t zero4 = {0.f, 0.f, 0.f, 0.f};
    f4_t acc[4][4];
    #pragma unroll
    for (int i = 0; i < 4; ++i)
        #pragma unroll
        for (int j = 0; j < 4; ++j) acc[i][j] = zero4;

    const int ra0 = tid >> 2,         pa0 = tid & 3;
    const int ra1 = (tid + 256) >> 2, pa1 = (tid + 256) & 3;
    const ushort* Ap0 = A  + (size_t)(row0 + ra0) * 2048 + pa0 * 8;
    const ushort* Ap1 = A  + (size_t)(row0 + ra1) * 2048 + pa1 * 8;
    const ushort* Bp0 = Bt + (size_t)(col0 + ra0) * 2048 + pa0 * 8;
    const ushort* Bp1 = Bt + (size_t)(col0 + ra1) * 2048 + pa1 * 8;

    uint4 sa0 = *(const uint4*)Ap0, sa1 = *(const uint4*)Ap1;
    uint4 sb0 = *(const uint4*)Bp0, sb1 = *(const uint4*)Bp1;

    for (int k0 = 0; k0 < 2048; k0 += 32) {
        *(uint4*)&Al[ra0 * 32 + pa0 * 8] = sa0;
        *(uint4*)&Al[ra1 * 32 + pa1 * 8] = sa1;
        *(uint4*)&Bl[ra0 * 32 + pa0 * 8] = sb0;
        *(uint4*)&Bl[ra1 * 32 + pa1 * 8] = sb1;
        __syncthreads();
        if (k0 + 32 < 2048) {
            sa0 = *(const uint4*)(Ap0 + k0 + 32);
            sa1 = *(const uint4*)(Ap1 + k0 + 32);
            sb0 = *(const uint4*)(Bp0 + k0 + 32);
            sb1 = *(const uint4*)(Bp1 + k0 + 32);
        }
        bh8_t af[4], bf[4];
        #pragma unroll
        for (int mf = 0; mf < 4; ++mf)
            af[mf] = *(const bh8_t*)&Al[(wr * 64 + mf * 16 + lr) * 32 + bk * 8];
        #pragma unroll
        for (int nf = 0; nf < 4; ++nf)
            bf[nf] = *(const bh8_t*)&Bl[(wc * 64 + nf * 16 + lr) * 32 + bk * 8];
        #pragma unroll
        for (int mf = 0; mf < 4; ++mf)
            #pragma unroll
            for (int nf = 0; nf < 4; ++nf)
                acc[mf][nf] = __builtin_amdgcn_mfma_f32_16x16x32_bf16(
                    af[mf], bf[nf], acc[mf][nf], 0, 0, 0);
        __syncthreads();
    }

    #pragma unroll
    for (int nf = 0; nf < 4; ++nf) {
        int n = col0 + wc * 64 + nf * 16 + lr;
        float bv = bias[n];
        #pragma unroll
        for (int mf = 0; mf < 4; ++mf) {
            int mbase = row0 + wr * 64 + mf * 16 + bk * 4;
            #pragma unroll
            for (int r = 0; r < 4; ++r)
                out[(size_t)(mbase + r) * 2048 + n] = acc[mf][nf][r] + bv;
        }
    }
}

// ---------------------------------------------------------------------------
extern "C" void kernel_launch(void* const* d_in, const int* in_sizes, int n_in,
                              void* d_out, int out_size, void* d_ws, size_t ws_size,
                              hipStream_t stream)
{
    (void)in_sizes; (void)n_in; (void)out_size; (void)ws_size;
    const float* x     = (const float*)d_in[0];
    const float* cosn  = (const float*)d_in[1];
    const float* sinn  = (const float*)d_in[2];
    const float* qkv_w = (const float*)d_in[3];
    const float* qkv_b = (const float*)d_in[4];
    const float* out_w = (const float*)d_in[5];
    const float* out_b = (const float*)d_in[6];

    char* ws = (char*)d_ws;
    ushort* xb   = (ushort*)(ws);                          // 16 MB [4096][2048]
    ushort* wtb  = (ushort*)(ws + ((size_t)16 << 20));     // 24 MB [6144][2048]
    ushort* owtb = (ushort*)(ws + ((size_t)40 << 20));     //  8 MB [2048][2048]
    ushort* Qb   = (ushort*)(ws + ((size_t)48 << 20));     // 16 MB head-major
    ushort* Kb   = (ushort*)(ws + ((size_t)64 << 20));     // 16 MB
    ushort* Vb   = (ushort*)(ws + ((size_t)80 << 20));     // 16 MB
    ushort* AO   = (ushort*)(ws + ((size_t)96 << 20));     // 16 MB [4096][2048]

    hipLaunchKernelGGL(cvt_f32_bf16, dim3(4096), dim3(256), 0, stream, x, xb);
    hipLaunchKernelGGL(transp_f32_bf16, dim3(96, 32), dim3(256), 0, stream,
                       qkv_w, wtb, 2048, 6144);
    hipLaunchKernelGGL(transp_f32_bf16, dim3(32, 32), dim3(256), 0, stream,
                       out_w, owtb, 2048, 2048);
    hipLaunchKernelGGL(qkv_gemm, dim3(32, 48), dim3(256), 0, stream,
                       xb, wtb, qkv_b, Qb, Kb, Vb);
    hipLaunchKernelGGL(rope_bf16, dim3(8192), dim3(256), 0, stream,
                       Qb, Kb, cosn, sinn);
    hipLaunchKernelGGL(attn_mfma, dim3(32, 32), dim3(256), 0, stream,
                       Qb, Kb, Vb, AO);
    hipLaunchKernelGGL(out_gemm, dim3(32, 16), dim3(256), 0, stream,
                       AO, owtb, out_b, (float*)d_out);
}

// Round 6
// 408.517 us; speedup vs baseline: 13.3337x; 1.4667x over previous
//
#include <hip/hip_runtime.h>
#include <cstddef>
#include <cstdint>

// ---------------- types / helpers ----------------
typedef __attribute__((ext_vector_type(8))) short bh8_t;  // 8 bf16 (4 VGPRs)
typedef __attribute__((ext_vector_type(4))) float f4_t;   // MFMA accumulator

__device__ __forceinline__ unsigned short f2bf(float x) {
    union { float f; unsigned u; } v; v.f = x;
    unsigned r = v.u + 0x7fffu + ((v.u >> 16) & 1u);   // RN-even
    return (unsigned short)(r >> 16);
}
__device__ __forceinline__ float bf2f(unsigned short u) {
    union { unsigned u; float f; } v; v.u = ((unsigned)u) << 16;
    return v.f;
}

// async global->LDS, 16B per lane. dest = wave-uniform base + lane*16.
__device__ __forceinline__ void gl_lds16(const void* g, void* l) {
    __builtin_amdgcn_global_load_lds(
        (const __attribute__((address_space(1))) unsigned int*)g,
        (__attribute__((address_space(3))) unsigned int*)l, 16, 0, 0);
}

// Problem constants
#define B_    2
#define S_    2048
#define D_    2048
#define H_    16
#define HD_   128

// ---------------------------------------------------------------------------
// x (f32) -> bf16, same layout. 8 elems/thread.
// ---------------------------------------------------------------------------
__global__ __launch_bounds__(256) void cvt_f32_bf16(const float* __restrict__ in,
                                                    ushort* __restrict__ out) {
    size_t i = ((size_t)blockIdx.x * 256 + threadIdx.x) * 8;
    float4 a = *(const float4*)&in[i];
    float4 b = *(const float4*)&in[i + 4];
    ushort4 o0, o1;
    o0.x = f2bf(a.x); o0.y = f2bf(a.y); o0.z = f2bf(a.z); o0.w = f2bf(a.w);
    o1.x = f2bf(b.x); o1.y = f2bf(b.y); o1.z = f2bf(b.z); o1.w = f2bf(b.w);
    *(ushort4*)&out[i]     = o0;
    *(ushort4*)&out[i + 4] = o1;
}

// ---------------------------------------------------------------------------
// W[R][C] f32  ->  Wt[C][R] bf16   (64x64 LDS tile transpose)
// ---------------------------------------------------------------------------
__global__ __launch_bounds__(256) void transp_f32_bf16(const float* __restrict__ in,
                                                       ushort* __restrict__ out,
                                                       int R, int C) {
    __shared__ float T[64][68];
    const int t = threadIdx.x, rl = t >> 4, cl = t & 15;
    const int r0 = blockIdx.y * 64, c0 = blockIdx.x * 64;
    #pragma unroll
    for (int j = 0; j < 4; ++j) {
        int row = rl + 16 * j;
        float4 v = *(const float4*)&in[(size_t)(r0 + row) * C + c0 + cl * 4];
        *(float4*)&T[row][cl * 4] = v;
    }
    __syncthreads();
    #pragma unroll
    for (int j = 0; j < 4; ++j) {
        int row = rl + 16 * j;
        ushort4 o;
        o.x = f2bf(T[cl * 4 + 0][row]);
        o.y = f2bf(T[cl * 4 + 1][row]);
        o.z = f2bf(T[cl * 4 + 2][row]);
        o.w = f2bf(T[cl * 4 + 3][row]);
        *(ushort4*)&out[(size_t)(c0 + row) * R + r0 + cl * 4] = o;
    }
}

// ---------------------------------------------------------------------------
// QKV GEMM: C[4096][6144] = xb * wtb^T + bias. 128x128 tile, BK=32,
// global_load_lds staging (m97 structure). Q,K -> head-major bf16; V -> Vtg
// (pre-transposed [bh][d][s'] with pi key-permutation: pos=8a+4h+r <-> key=4a+16h+r).
// ---------------------------------------------------------------------------
__global__ __launch_bounds__(256) void qkv_gemm(const ushort* __restrict__ A,
                                                const ushort* __restrict__ Bt,
                                                const float* __restrict__ bias,
                                                ushort* __restrict__ Qb,
                                                ushort* __restrict__ Kb,
                                                ushort* __restrict__ Vtg) {
    __shared__ ushort Al[128 * 32];
    __shared__ ushort Bl[128 * 32];
    const int tid = threadIdx.x;
    const int l = tid & 63, wv = tid >> 6;
    const int lr = l & 15, bk = l >> 4;
    const int wr = wv >> 1, wc = wv & 1;
    const int row0 = blockIdx.x * 128, col0 = blockIdx.y * 128;

    f4_t zero4 = {0.f, 0.f, 0.f, 0.f};
    f4_t acc[4][4];
    #pragma unroll
    for (int i = 0; i < 4; ++i)
        #pragma unroll
        for (int j = 0; j < 4; ++j) acc[i][j] = zero4;

    const int c0 = tid, c1 = tid + 256;         // 16B chunk ids (512 per tile)
    const ushort* Ap0 = A  + (size_t)(row0 + (c0 >> 2)) * 2048 + (c0 & 3) * 8;
    const ushort* Ap1 = A  + (size_t)(row0 + (c1 >> 2)) * 2048 + (c1 & 3) * 8;
    const ushort* Bp0 = Bt + (size_t)(col0 + (c0 >> 2)) * 2048 + (c0 & 3) * 8;
    const ushort* Bp1 = Bt + (size_t)(col0 + (c1 >> 2)) * 2048 + (c1 & 3) * 8;
    ushort* Ad0 = Al + (size_t)(c0 - l) * 8;
    ushort* Ad1 = Al + (size_t)(c1 - l) * 8;
    ushort* Bd0 = Bl + (size_t)(c0 - l) * 8;
    ushort* Bd1 = Bl + (size_t)(c1 - l) * 8;

    for (int k0 = 0; k0 < 2048; k0 += 32) {
        gl_lds16(Ap0 + k0, Ad0);
        gl_lds16(Ap1 + k0, Ad1);
        gl_lds16(Bp0 + k0, Bd0);
        gl_lds16(Bp1 + k0, Bd1);
        __syncthreads();
        bh8_t af[4], bf[4];
        #pragma unroll
        for (int mf = 0; mf < 4; ++mf)
            af[mf] = *(const bh8_t*)&Al[(wr * 64 + mf * 16 + lr) * 32 + bk * 8];
        #pragma unroll
        for (int nf = 0; nf < 4; ++nf)
            bf[nf] = *(const bh8_t*)&Bl[(wc * 64 + nf * 16 + lr) * 32 + bk * 8];
        #pragma unroll
        for (int mf = 0; mf < 4; ++mf)
            #pragma unroll
            for (int nf = 0; nf < 4; ++nf)
                acc[mf][nf] = __builtin_amdgcn_mfma_f32_16x16x32_bf16(
                    af[mf], bf[nf], acc[mf][nf], 0, 0, 0);
        __syncthreads();
    }

    const int which = col0 >> 11;
    const int h = (col0 & 2047) >> 7;
    if (which < 2) {
        ushort* dst = which == 0 ? Qb : Kb;
        #pragma unroll
        for (int nf = 0; nf < 4; ++nf) {
            int n = col0 + wc * 64 + nf * 16 + lr;
            float bv = bias[n];
            int hd = (n & 2047) & 127;
            #pragma unroll
            for (int mf = 0; mf < 4; ++mf) {
                int mbase = row0 + wr * 64 + mf * 16 + bk * 4;
                #pragma unroll
                for (int r = 0; r < 4; ++r) {
                    int m = mbase + r;
                    int b = m >> 11, s = m & 2047;
                    dst[((size_t)(b * 16 + h) * 2048 + s) * 128 + hd] =
                        f2bf(acc[mf][nf][r] + bv);
                }
            }
        }
    } else {
        // V: write transposed+permuted: Vtg[(b*16+h)*128+hd][spos], 8B stores
        #pragma unroll
        for (int nf = 0; nf < 4; ++nf) {
            int n = col0 + wc * 64 + nf * 16 + lr;
            float bv = bias[n];
            int hd = n & 127;
            #pragma unroll
            for (int mf = 0; mf < 4; ++mf) {
                int mbase = row0 + wr * 64 + mf * 16 + bk * 4;
                int b = mbase >> 11, s4 = mbase & 2047;
                int spos = (s4 & ~31) | (((s4 >> 2) & 3) << 3) | (((s4 >> 4) & 1) << 2);
                ushort4 o;
                o.x = f2bf(acc[mf][nf][0] + bv);
                o.y = f2bf(acc[mf][nf][1] + bv);
                o.z = f2bf(acc[mf][nf][2] + bv);
                o.w = f2bf(acc[mf][nf][3] + bv);
                *(ushort4*)&Vtg[((size_t)((b * 16 + h) * 128 + hd)) * 2048 + spos] = o;
            }
        }
    }
}

// ---------------------------------------------------------------------------
// RoPE in place on bf16 Qb/Kb. Q pre-scaled by 1/sqrt(128).
// ---------------------------------------------------------------------------
__global__ __launch_bounds__(256) void rope_bf16(ushort* __restrict__ Qb,
                                                 ushort* __restrict__ Kb,
                                                 const float* __restrict__ cosn,
                                                 const float* __restrict__ sinn) {
    unsigned idx = blockIdx.x * 256 + threadIdx.x;
    int regn = idx >> 20;
    unsigned rest = idx & 1048575u;
    unsigned row = rest >> 4;
    int g = rest & 15;
    int s = row & 2047;
    ushort* base = (regn ? Kb : Qb) + (size_t)row * 128 + g * 4;
    uint2 lo = *(const uint2*)base;
    uint2 hi = *(const uint2*)(base + 64);
    float4 c4 = *(const float4*)&cosn[s * 128 + g * 4];
    float4 s4 = *(const float4*)&sinn[s * 128 + g * 4];
    const float sc = regn ? 1.0f : 0.08838834764831845f;
    const ushort* lp = (const ushort*)&lo;
    const ushort* hp = (const ushort*)&hi;
    float cf[4] = {c4.x, c4.y, c4.z, c4.w};
    float sf[4] = {s4.x, s4.y, s4.z, s4.w};
    ushort4 olo, ohi;
    ushort* olp = (ushort*)&olo;
    ushort* ohp = (ushort*)&ohi;
    #pragma unroll
    for (int e = 0; e < 4; ++e) {
        float lv = bf2f(lp[e]), hv = bf2f(hp[e]);
        olp[e] = f2bf((lv * cf[e] - hv * sf[e]) * sc);
        ohp[e] = f2bf((hv * cf[e] + lv * sf[e]) * sc);
    }
    *(ushort4*)base        = olo;
    *(ushort4*)(base + 64) = ohi;
}

// ---------------------------------------------------------------------------
// Flash attention v2: gl_lds staging (pre-swizzled source), double-buffered
// K/V tiles, counted vmcnt(8), setprio around MFMA. 64 q-rows/block.
// K LDS: [key][128] ^((key&7)<<4).  V LDS: [d][64pos] ^((d&7)<<4), pos=pi(key).
// ---------------------------------------------------------------------------
__global__ __launch_bounds__(256) void attn2(const ushort* __restrict__ Qb,
                                             const ushort* __restrict__ Kb,
                                             const ushort* __restrict__ Vtg,
                                             ushort* __restrict__ AO) {
    __shared__ ushort lds[2][16384];   // per buf: K 8192 ushorts + V 8192
    const int tid = threadIdx.x;
    const int l = tid & 63, wq = tid >> 6;
    const int lr = l & 15, bk = l >> 4;
    const int id = blockIdx.x;
    const int bh = id & 31;                 // id%8 == bh%8 -> same bh on one XCD
    const int qb = 31 - (id >> 5);          // heavy blocks first
    const int q0 = qb * 64;
    const int qrow = q0 + wq * 16 + lr;
    const ushort* Qg = Qb + ((size_t)bh * 2048 + qrow) * 128;
    const ushort* KgB = Kb + (size_t)bh * 2048 * 128;
    const ushort* VgB = Vtg + (size_t)bh * 128 * 2048;

    bh8_t qf[4];
    #pragma unroll
    for (int ks = 0; ks < 4; ++ks)
        qf[ks] = *(const bh8_t*)(Qg + ks * 32 + bk * 8);

    float mrun = -1e30f, lrun = 0.f;
    f4_t zero4 = {0.f, 0.f, 0.f, 0.f};
    f4_t oacc[8];
    #pragma unroll
    for (int i = 0; i < 8; ++i) oacc[i] = zero4;

    auto issue = [&](int kt, int buf) {
        ushort* Kl = &lds[buf][0];
        ushort* Vl = &lds[buf][8192];
        const ushort* Kg = KgB + (size_t)kt * 64 * 128;
        #pragma unroll
        for (int i = 0; i < 4; ++i) {
            int c = tid + 256 * i;
            int key = c >> 4, d8 = (c & 15) ^ (key & 7);
            gl_lds16(Kg + key * 128 + d8 * 8, Kl + (size_t)(c - l) * 8);
        }
        #pragma unroll
        for (int i = 0; i < 4; ++i) {
            int c = tid + 256 * i;
            int d = c >> 3, p8 = (c & 7) ^ (d & 7);
            gl_lds16(VgB + (size_t)d * 2048 + kt * 64 + p8 * 8,
                     Vl + (size_t)(c - l) * 8);
        }
    };

    issue(0, 0);
    for (int kt = 0; kt <= qb; ++kt) {
        const int buf = kt & 1;
        if (kt < qb) {
            issue(kt + 1, buf ^ 1);
            asm volatile("s_waitcnt vmcnt(8)" ::: "memory");
        } else {
            asm volatile("s_waitcnt vmcnt(0)" ::: "memory");
        }
        __builtin_amdgcn_s_barrier();
        asm volatile("" ::: "memory");
        const char* Kl = (const char*)&lds[buf][0];
        const char* Vl = (const char*)&lds[buf][8192];

        // ---- S^T = K * Q^T ----
        f4_t sacc[4];
        #pragma unroll
        for (int kf = 0; kf < 4; ++kf) sacc[kf] = zero4;
        __builtin_amdgcn_s_setprio(1);
        #pragma unroll
        for (int ks = 0; ks < 4; ++ks)
            #pragma unroll
            for (int kf = 0; kf < 4; ++kf) {
                int key = kf * 16 + lr;
                int ab = (key * 256 + ks * 64 + bk * 16) ^ ((key & 7) << 4);
                bh8_t kv = *(const bh8_t*)(Kl + ab);
                sacc[kf] = __builtin_amdgcn_mfma_f32_16x16x32_bf16(
                    kv, qf[ks], sacc[kf], 0, 0, 0);
            }
        __builtin_amdgcn_s_setprio(0);

        if (kt == qb) {   // causal mask on diagonal tile
            #pragma unroll
            for (int kf = 0; kf < 4; ++kf)
                #pragma unroll
                for (int r = 0; r < 4; ++r) {
                    int key = kt * 64 + kf * 16 + bk * 4 + r;
                    if (key > qrow) sacc[kf][r] = -1e30f;
                }
        }
        // ---- online softmax ----
        float mt = -1e30f;
        #pragma unroll
        for (int kf = 0; kf < 4; ++kf)
            #pragma unroll
            for (int r = 0; r < 4; ++r) mt = fmaxf(mt, sacc[kf][r]);
        mt = fmaxf(mt, __shfl_xor(mt, 16));
        mt = fmaxf(mt, __shfl_xor(mt, 32));
        float mnew = fmaxf(mrun, mt);
        float alpha = __expf(mrun - mnew);
        float rsum = 0.f;
        #pragma unroll
        for (int kf = 0; kf < 4; ++kf)
            #pragma unroll
            for (int r = 0; r < 4; ++r) {
                float p = __expf(sacc[kf][r] - mnew);
                sacc[kf][r] = p;
                rsum += p;
            }
        rsum += __shfl_xor(rsum, 16);
        rsum += __shfl_xor(rsum, 32);
        lrun = lrun * alpha + rsum;
        mrun = mnew;
        #pragma unroll
        for (int df = 0; df < 8; ++df) oacc[df] *= alpha;

        // ---- pack P^T (key order: ks2*32 + {bk*4+r, 16+bk*4+r}) ----
        union { unsigned u[4]; bh8_t v; } bop[2];
        #pragma unroll
        for (int ks2 = 0; ks2 < 2; ++ks2)
            #pragma unroll
            for (int e = 0; e < 8; e += 2) {
                unsigned lo16 = f2bf(sacc[2 * ks2 + (e >> 2)][e & 3]);
                unsigned hi16 = f2bf(sacc[2 * ks2 + ((e + 1) >> 2)][(e + 1) & 3]);
                bop[ks2].u[e >> 1] = lo16 | (hi16 << 16);
            }
        // ---- O^T += V^T * P^T ----
        __builtin_amdgcn_s_setprio(1);
        #pragma unroll
        for (int df = 0; df < 8; ++df) {
            int d = df * 16 + lr;
            #pragma unroll
            for (int ks2 = 0; ks2 < 2; ++ks2) {
                int ab = (d * 128 + ks2 * 64 + bk * 16) ^ ((d & 7) << 4);
                bh8_t av = *(const bh8_t*)(Vl + ab);
                oacc[df] = __builtin_amdgcn_mfma_f32_16x16x32_bf16(
                    av, bop[ks2].v, oacc[df], 0, 0, 0);
            }
        }
        __builtin_amdgcn_s_setprio(0);
        asm volatile("" ::: "memory");
        __builtin_amdgcn_s_barrier();
        asm volatile("" ::: "memory");
    }

    // ---- normalize + store bf16 to AO[B*S][D] ----
    float inv = 1.0f / lrun;
    const int b = bh >> 4, h = bh & 15;
    #pragma unroll
    for (int df = 0; df < 8; ++df) {
        ushort4 o;
        o.x = f2bf(oacc[df][0] * inv);
        o.y = f2bf(oacc[df][1] * inv);
        o.z = f2bf(oacc[df][2] * inv);
        o.w = f2bf(oacc[df][3] * inv);
        size_t off = ((size_t)(b * 2048 + qrow)) * 2048 + h * 128 + df * 16 + bk * 4;
        *(ushort4*)&AO[off] = o;
    }
}

// ---------------------------------------------------------------------------
// Out projection: out[4096][2048] = AO * owtb^T + b (f32 out), gl_lds staging.
// ---------------------------------------------------------------------------
__global__ __launch_bounds__(256) void out_gemm(const ushort* __restrict__ A,
                                                const ushort* __restrict__ Bt,
                                                const float* __restrict__ bias,
                                                float* __restrict__ out) {
    __shared__ ushort Al[128 * 32];
    __shared__ ushort Bl[128 * 32];
    const int tid = threadIdx.x;
    const int l = tid & 63, wv = tid >> 6;
    const int lr = l & 15, bk = l >> 4;
    const int wr = wv >> 1, wc = wv & 1;
    const int row0 = blockIdx.x * 128, col0 = blockIdx.y * 128;

    f4_t zero4 = {0.f, 0.f, 0.f, 0.f};
    f4_t acc[4][4];
    #pragma unroll
    for (int i = 0; i < 4; ++i)
        #pragma unroll
        for (int j = 0; j < 4; ++j) acc[i][j] = zero4;

    const int c0 = tid, c1 = tid + 256;
    const ushort* Ap0 = A  + (size_t)(row0 + (c0 >> 2)) * 2048 + (c0 & 3) * 8;
    const ushort* Ap1 = A  + (size_t)(row0 + (c1 >> 2)) * 2048 + (c1 & 3) * 8;
    const ushort* Bp0 = Bt + (size_t)(col0 + (c0 >> 2)) * 2048 + (c0 & 3) * 8;
    const ushort* Bp1 = Bt + (size_t)(col0 + (c1 >> 2)) * 2048 + (c1 & 3) * 8;
    ushort* Ad0 = Al + (size_t)(c0 - l) * 8;
    ushort* Ad1 = Al + (size_t)(c1 - l) * 8;
    ushort* Bd0 = Bl + (size_t)(c0 - l) * 8;
    ushort* Bd1 = Bl + (size_t)(c1 - l) * 8;

    for (int k0 = 0; k0 < 2048; k0 += 32) {
        gl_lds16(Ap0 + k0, Ad0);
        gl_lds16(Ap1 + k0, Ad1);
        gl_lds16(Bp0 + k0, Bd0);
        gl_lds16(Bp1 + k0, Bd1);
        __syncthreads();
        bh8_t af[4], bf[4];
        #pragma unroll
        for (int mf = 0; mf < 4; ++mf)
            af[mf] = *(const bh8_t*)&Al[(wr * 64 + mf * 16 + lr) * 32 + bk * 8];
        #pragma unroll
        for (int nf = 0; nf < 4; ++nf)
            bf[nf] = *(const bh8_t*)&Bl[(wc * 64 + nf * 16 + lr) * 32 + bk * 8];
        #pragma unroll
        for (int mf = 0; mf < 4; ++mf)
            #pragma unroll
            for (int nf = 0; nf < 4; ++nf)
                acc[mf][nf] = __builtin_amdgcn_mfma_f32_16x16x32_bf16(
                    af[mf], bf[nf], acc[mf][nf], 0, 0, 0);
        __syncthreads();
    }

    #pragma unroll
    for (int nf = 0; nf < 4; ++nf) {
        int n = col0 + wc * 64 + nf * 16 + lr;
        float bv = bias[n];
        #pragma unroll
        for (int mf = 0; mf < 4; ++mf) {
            int mbase = row0 + wr * 64 + mf * 16 + bk * 4;
            #pragma unroll
            for (int r = 0; r < 4; ++r)
                out[(size_t)(mbase + r) * 2048 + n] = acc[mf][nf][r] + bv;
        }
    }
}

// ---------------------------------------------------------------------------
extern "C" void kernel_launch(void* const* d_in, const int* in_sizes, int n_in,
                              void* d_out, int out_size, void* d_ws, size_t ws_size,
                              hipStream_t stream)
{
    (void)in_sizes; (void)n_in; (void)out_size; (void)ws_size;
    const float* x     = (const float*)d_in[0];
    const float* cosn  = (const float*)d_in[1];
    const float* sinn  = (const float*)d_in[2];
    const float* qkv_w = (const float*)d_in[3];
    const float* qkv_b = (const float*)d_in[4];
    const float* out_w = (const float*)d_in[5];
    const float* out_b = (const float*)d_in[6];

    char* ws = (char*)d_ws;
    ushort* xb   = (ushort*)(ws);                          // 16 MB [4096][2048]
    ushort* wtb  = (ushort*)(ws + ((size_t)16 << 20));     // 24 MB [6144][2048]
    ushort* owtb = (ushort*)(ws + ((size_t)40 << 20));     //  8 MB [2048][2048]
    ushort* Qb   = (ushort*)(ws + ((size_t)48 << 20));     // 16 MB head-major
    ushort* Kb   = (ushort*)(ws + ((size_t)64 << 20));     // 16 MB head-major
    ushort* Vtg  = (ushort*)(ws + ((size_t)80 << 20));     // 16 MB [bh][d][s']
    ushort* AO   = (ushort*)(ws + ((size_t)96 << 20));     // 16 MB [4096][2048]

    hipLaunchKernelGGL(cvt_f32_bf16, dim3(4096), dim3(256), 0, stream, x, xb);
    hipLaunchKernelGGL(transp_f32_bf16, dim3(96, 32), dim3(256), 0, stream,
                       qkv_w, wtb, 2048, 6144);
    hipLaunchKernelGGL(transp_f32_bf16, dim3(32, 32), dim3(256), 0, stream,
                       out_w, owtb, 2048, 2048);
    hipLaunchKernelGGL(qkv_gemm, dim3(32, 48), dim3(256), 0, stream,
                       xb, wtb, qkv_b, Qb, Kb, Vtg);
    hipLaunchKernelGGL(rope_bf16, dim3(8192), dim3(256), 0, stream,
                       Qb, Kb, cosn, sinn);
    hipLaunchKernelGGL(attn2, dim3(1024), dim3(256), 0, stream,
                       Qb, Kb, Vtg, AO);
    hipLaunchKernelGGL(out_gemm, dim3(32, 16), dim3(256), 0, stream,
                       AO, owtb, out_b, (float*)d_out);
}